// Round 7
// baseline (311.336 us; speedup 1.0000x reference)
//
#include <hip/hip_runtime.h>
#include <hip/hip_bf16.h>
#include <cstddef>

// ---------------- problem constants ----------------
#define DMODEL  768
#define DINNER  1536
#define DSTATE  64
#define NH      24
#define HD      64
#define CONVD   1664      // DINNER + 2*DSTATE
#define DINPROJ 3224      // 2*DINNER + 2*DSTATE + NH
#define SEQ     4096
#define BSZ     2
#define NTOK    8192      // BSZ*SEQ
#define NCHUNK  64        // SEQ/64
#define EPSF    1e-5f
#define LP      72        // LDS pitch (shorts) for SSD kernels

typedef __attribute__((ext_vector_type(8))) short  short8;
typedef __attribute__((ext_vector_type(4))) float  f32x4;
typedef unsigned long long ull;

// ---------------- helpers ----------------
__device__ __forceinline__ unsigned short f2bf(float f) {
  union { float f; unsigned int u; } v; v.f = f;
  unsigned int r = v.u + 0x7fffu + ((v.u >> 16) & 1u);   // RNE
  return (unsigned short)(r >> 16);
}
__device__ __forceinline__ float bf2f(unsigned short u) {
  union { unsigned int i; float f; } v; v.i = ((unsigned int)u) << 16; return v.f;
}
__device__ __forceinline__ ull pack4bf(float a, float b, float c, float d) {
  return (ull)(f2bf(a) | ((unsigned int)f2bf(b) << 16))
       | ((ull)(f2bf(c) | ((unsigned int)f2bf(d) << 16)) << 32);
}
__device__ __forceinline__ float sigm(float x) { return 1.f / (1.f + __expf(-x)); }

// async 16B global -> LDS (lane i of the wave lands at ldsbase + i*16)
__device__ __forceinline__ void gld16(const unsigned short* g, unsigned short* l) {
  __builtin_amdgcn_global_load_lds(
      (const __attribute__((address_space(1))) unsigned int*)g,
      (__attribute__((address_space(3))) unsigned int*)l, 16, 0, 0);
}

// ---------------- merged prep: LayerNorm (ids 0..8191) + 4 weight transposes ------
__global__ __launch_bounds__(256) void k_prep(const float* __restrict__ x,
    const float* __restrict__ lw, const float* __restrict__ lb,
    unsigned short* __restrict__ xn, float* __restrict__ ssq,
    const float* __restrict__ W0, unsigned short* __restrict__ T0,
    const float* __restrict__ W1, unsigned short* __restrict__ T1,
    const float* __restrict__ W2, unsigned short* __restrict__ T2,
    const float* __restrict__ W3, unsigned short* __restrict__ T3,
    const float* __restrict__ rmsw)
{
  const int id = blockIdx.x, tid = threadIdx.x;
  if (id < NTOK) {
    __shared__ float red[4];
    if (id < 32) ssq[id * 256 + tid] = 0.f;          // 8192 f32 = 32x256
    const float* xr = x + (size_t)id * DMODEL;
    float v[3]; float s = 0.f;
    #pragma unroll
    for (int q = 0; q < 3; q++) { v[q] = xr[q*256 + tid]; s += v[q]; }
    #pragma unroll
    for (int off = 32; off; off >>= 1) s += __shfl_down(s, off);
    if ((tid & 63) == 0) red[tid >> 6] = s;
    __syncthreads();
    const float mu = (red[0] + red[1] + red[2] + red[3]) * (1.f / DMODEL);
    __syncthreads();
    float s2 = 0.f;
    #pragma unroll
    for (int q = 0; q < 3; q++) { float d = v[q] - mu; s2 += d * d; }
    #pragma unroll
    for (int off = 32; off; off >>= 1) s2 += __shfl_down(s2, off);
    if ((tid & 63) == 0) red[tid >> 6] = s2;
    __syncthreads();
    const float rs = rsqrtf((red[0] + red[1] + red[2] + red[3]) * (1.f / DMODEL) + EPSF);
    unsigned short* xo = xn + (size_t)id * DMODEL;
    #pragma unroll
    for (int q = 0; q < 3; q++) {
      int col = q*256 + tid;
      xo[col] = f2bf((v[q] - mu) * rs * lw[col] + lb[col]);
    }
  } else {
    int wt = id - NTOK;
    const float* W; unsigned short* T; int K, N, nt; const float* scale = nullptr;
    if (wt < 2424)      { W = W0; T = T0; K = 768;  N = 3224; nt = 101; }
    else if (wt < 3000) { W = W1; T = T1; K = 768;  N = 768;  nt = 24; wt -= 2424; }
    else if (wt < 4152) { W = W2; T = T2; K = 1536; N = 768;  nt = 24; wt -= 3000; scale = rmsw; }
    else                { W = W3; T = T3; K = 768;  N = 768;  nt = 24; wt -= 4152; }
    const int n0 = (wt % nt) * 32, k0 = (wt / nt) * 32;
    __shared__ float tile[32][33];
    const int tx = tid & 31, ty = tid >> 5;           // 32 x 8
    #pragma unroll
    for (int r = 0; r < 4; r++) {
      int k = k0 + ty + 8*r;
      if (k < K && n0 + tx < N) tile[ty + 8*r][tx] = W[(size_t)k * N + n0 + tx];
    }
    __syncthreads();
    #pragma unroll
    for (int r = 0; r < 4; r++) {
      int n = n0 + ty + 8*r, k = k0 + tx;
      if (n < N && k < K) {
        float v = tile[tx][ty + 8*r];
        if (scale) v *= scale[k];
        T[(size_t)n * K + k] = f2bf(v);
      }
    }
  }
}

// ---------------- shared GEMM helpers ----------------
template<int MIB, int NACC>
__device__ __forceinline__ void mfma16t(f32x4 (&acc)[NACC][4], const short8 (&a_)[4],
                                        const short8 (&bK)[4]) {
  __builtin_amdgcn_s_setprio(1);
  #pragma unroll
  for (int mi = 0; mi < 4; mi++)
    #pragma unroll
    for (int ni = 0; ni < 4; ni++)
      acc[MIB + mi][ni] =
          __builtin_amdgcn_mfma_f32_16x16x32_bf16(bK[ni], a_[mi], acc[MIB + mi][ni], 0, 0, 0);
  __builtin_amdgcn_s_setprio(0);
}

__device__ __forceinline__ short8 lds8(const unsigned short* L, int off) {
  return *(const short8*)(&L[off]);
}

#define FENCE() asm volatile("" ::: "memory")
#define BARX() do { __builtin_amdgcn_sched_barrier(0); FENCE(); \
  __builtin_amdgcn_s_barrier(); FENCE(); __builtin_amdgcn_sched_barrier(0); } while (0)
#define VW6() asm volatile("s_waitcnt vmcnt(6)" ::: "memory")
#define VW2() asm volatile("s_waitcnt vmcnt(2)" ::: "memory")

// ================= 256x256 8-PHASE GEMM core (K=768 fixed) =======================
// (R2-proven. 512 thr = 8 waves 2Mx4N; LDS 128 KiB; swapped MFMA -> lane holds
//  4 consecutive columns; peeled tail leaves vmcnt clean for next tile.)
#define PH_LDA(BUF, MIBASE, AOFF) do { \
  a_[0] = lds8(L, (BUF) + arow + ((MIBASE)+0)*1024 + (AOFF)); \
  a_[1] = lds8(L, (BUF) + arow + ((MIBASE)+1)*1024 + (AOFF)); \
  a_[2] = lds8(L, (BUF) + arow + ((MIBASE)+2)*1024 + (AOFF)); \
  a_[3] = lds8(L, (BUF) + arow + ((MIBASE)+3)*1024 + (AOFF)); } while (0)

#define PH_LDB(BUF, KS) do { \
  bK[0] = lds8(L, brow + (BUF) + (KS)*8192 + 0*512 + boff); \
  bK[1] = lds8(L, brow + (BUF) + (KS)*8192 + 1*512 + boff); \
  bK[2] = lds8(L, brow + (BUF) + (KS)*8192 + 2*512 + boff); \
  bK[3] = lds8(L, brow + (BUF) + (KS)*8192 + 3*512 + boff); } while (0)

__device__ __forceinline__ void gemm256(const unsigned short* __restrict__ A,
    const unsigned short* __restrict__ Bt, unsigned short* __restrict__ Cb,
    int N, int m0, int n0, int epi, const float* __restrict__ bias,
    unsigned short* L)
{
  const int K = 768;                       // 12 K-tiles: j=0..4 full + peeled tail
  const int tid = threadIdx.x;
  const int lane = tid & 63, w = tid >> 6;
  const int wm2 = w >> 2, wn4 = w & 3;
  const int l15 = lane & 15, lq = lane >> 4;
  const int aoff0 = ((lq)     ^ (l15 & 7)) * 8;
  const int aoff1 = ((lq + 4) ^ (l15 & 7)) * 8;
  const int boff  = (lq ^ ((l15 >> 1) & 3)) * 8;
  const int arow = (wm2 * 128 + l15) * 64;
  const int brow = 32768 + (wn4 * 64 + l15) * 32;

  const int lr3 = lane >> 3, lr2 = lane >> 2;
  const int gqA = ((lane & 7) ^ lr3) * 8;
  const int gqB = ((lane & 3) ^ (lr3 & 3)) * 8;
  const unsigned short* sA0 = A + (size_t)(m0 + 8*w + lr3) * K + gqA;
  const unsigned short* sA1 = sA0 + (size_t)128 * K;
  const unsigned short* sA2 = sA0 + (size_t)64  * K;
  const unsigned short* sA3 = sA0 + (size_t)192 * K;
  int rb0 = n0 + 16*w + lr2;        if (rb0 > N - 1) rb0 = N - 1;
  int rb1 = n0 + 128 + 16*w + lr2;  if (rb1 > N - 1) rb1 = N - 1;
  const unsigned short* sB0 = Bt + (size_t)rb0 * K + gqB;
  const unsigned short* sB1 = Bt + (size_t)rb1 * K + gqB;

  const int dA0 = w*512, dA1 = (16+w)*512, dA2 = (8+w)*512, dA3 = (24+w)*512;
  const int dB0 = 32768 + w*512, dB1 = 32768 + (8+w)*512;

  f32x4 acc[8][4];
  #pragma unroll
  for (int i = 0; i < 8; i++)
    #pragma unroll
    for (int jj = 0; jj < 4; jj++) acc[i][jj] = (f32x4){0.f, 0.f, 0.f, 0.f};
  short8 bK[4];

  // ---- prologue ----
  gld16(sA0, &L[dA0]); gld16(sA1, &L[dA1]);
  gld16(sA2, &L[dA2]); gld16(sA3, &L[dA3]);
  gld16(sB0, &L[dB0]); gld16(sB1, &L[dB1]);
  gld16(sB0 + 32, &L[dB0 + 8192]); gld16(sB1 + 32, &L[dB1 + 8192]);
  gld16(sB0 + 64, &L[dB0 + 16384]); gld16(sB1 + 64, &L[dB1 + 16384]);
  gld16(sA0 + 64, &L[dA0 + 16384]); gld16(sA1 + 64, &L[dA1 + 16384]);
  gld16(sB0 + 96, &L[dB0 + 16384 + 8192]); gld16(sB1 + 96, &L[dB1 + 16384 + 8192]);
  VW6();
  FENCE(); __builtin_amdgcn_s_barrier(); FENCE(); __builtin_amdgcn_sched_barrier(0);

  #pragma unroll 1
  for (int j = 0; j < 5; j++) {
    const int kO1 = (2*j + 1) * 64;
    const int kE  = (2*j + 2) * 64;
    const int kO3 = (2*j + 3) * 64;
    short8 a_[4];

    PH_LDA(0, 0, aoff0); PH_LDB(0, 0);
    gld16(sA2 + kO1, &L[dA2 + 16384]); gld16(sA3 + kO1, &L[dA3 + 16384]);
    BARX(); mfma16t<0>(acc, a_, bK); BARX();
    PH_LDA(0, 4, aoff0);
    gld16(sB0 + kE, &L[dB0]); gld16(sB1 + kE, &L[dB1]);
    BARX(); mfma16t<4>(acc, a_, bK); BARX();
    PH_LDA(0, 0, aoff1); PH_LDB(0, 1);
    BARX(); mfma16t<0>(acc, a_, bK); BARX();
    PH_LDA(0, 4, aoff1);
    gld16(sA0 + kE, &L[dA0]); gld16(sA1 + kE, &L[dA1]);
    gld16(sB0 + kE + 32, &L[dB0 + 8192]); gld16(sB1 + kE + 32, &L[dB1 + 8192]);
    BARX(); mfma16t<4>(acc, a_, bK);
    __builtin_amdgcn_sched_barrier(0); VW6(); BARX();
    PH_LDA(16384, 0, aoff0); PH_LDB(16384, 0);
    gld16(sA2 + kE, &L[dA2]); gld16(sA3 + kE, &L[dA3]);
    BARX(); mfma16t<0>(acc, a_, bK); BARX();
    PH_LDA(16384, 4, aoff0);
    gld16(sB0 + kO3, &L[dB0 + 16384]); gld16(sB1 + kO3, &L[dB1 + 16384]);
    BARX(); mfma16t<4>(acc, a_, bK); BARX();
    PH_LDA(16384, 0, aoff1); PH_LDB(16384, 1);
    BARX(); mfma16t<0>(acc, a_, bK); BARX();
    PH_LDA(16384, 4, aoff1);
    gld16(sA0 + kO3, &L[dA0 + 16384]); gld16(sA1 + kO3, &L[dA1 + 16384]);
    gld16(sB0 + kO3 + 32, &L[dB0 + 16384 + 8192]); gld16(sB1 + kO3 + 32, &L[dB1 + 16384 + 8192]);
    BARX(); mfma16t<4>(acc, a_, bK);
    __builtin_amdgcn_sched_barrier(0); VW6(); BARX();
  }

  // ---- peeled tail (tiles 10/11): vmcnt clean at exit ----
  {
    short8 a_[4];
    PH_LDA(0, 0, aoff0); PH_LDB(0, 0);
    gld16(sA2 + 704, &L[dA2 + 16384]); gld16(sA3 + 704, &L[dA3 + 16384]);
    BARX(); mfma16t<0>(acc, a_, bK); BARX();
    PH_LDA(0, 4, aoff0);
    BARX(); mfma16t<4>(acc, a_, bK); BARX();
    PH_LDA(0, 0, aoff1); PH_LDB(0, 1);
    BARX(); mfma16t<0>(acc, a_, bK); BARX();
    PH_LDA(0, 4, aoff1);
    BARX(); mfma16t<4>(acc, a_, bK);
    __builtin_amdgcn_sched_barrier(0);
    asm volatile("s_waitcnt vmcnt(0)" ::: "memory");
    BARX();
    PH_LDA(16384, 0, aoff0); PH_LDB(16384, 0);
    BARX(); mfma16t<0>(acc, a_, bK); BARX();
    PH_LDA(16384, 4, aoff0);
    BARX(); mfma16t<4>(acc, a_, bK); BARX();
    PH_LDA(16384, 0, aoff1); PH_LDB(16384, 1);
    BARX(); mfma16t<0>(acc, a_, bK); BARX();
    PH_LDA(16384, 4, aoff1);
    BARX(); mfma16t<4>(acc, a_, bK); BARX();
  }

  // ---- epilogue ----
  const int mrow = m0 + wm2 * 128 + l15;
  const int ncb  = n0 + wn4 * 64 + 4 * lq;
  if (epi == 0) {
    #pragma unroll
    for (int mi = 0; mi < 8; mi++) {
      unsigned short* Crow = Cb + (size_t)(mrow + 16*mi) * N + ncb;
      #pragma unroll
      for (int ni = 0; ni < 4; ni++) {
        if (ncb + 16*ni < N) {
          f32x4 v = acc[mi][ni];
          *(ull*)(Crow + 16*ni) = pack4bf(v[0], v[1], v[2], v[3]);
        }
      }
    }
  } else {            // epi==1: sigmoid(C + bias[n]) (N=768)
    f32x4 bb[4];
    #pragma unroll
    for (int ni = 0; ni < 4; ni++) bb[ni] = *(const f32x4*)(bias + ncb + 16*ni);
    #pragma unroll
    for (int mi = 0; mi < 8; mi++) {
      unsigned short* Crow = Cb + (size_t)(mrow + 16*mi) * N + ncb;
      #pragma unroll
      for (int ni = 0; ni < 4; ni++) {
        f32x4 v = acc[mi][ni];
        *(ull*)(Crow + 16*ni) = pack4bf(
            sigm(v[0] + bb[ni][0]), sigm(v[1] + bb[ni][1]),
            sigm(v[2] + bb[ni][2]), sigm(v[3] + bb[ni][3]));
      }
    }
  }
}

// in_proj (13n x 32m tiles) + gate (3n x 32m): 256 persistent blocks x 2 STATIC
// tiles (same XCD, same A-panel pair -> L2-hot tile2 prologue). R2-proven mapping.
__global__ __launch_bounds__(512, 2) void k_ipg256(
    const unsigned short* __restrict__ XN, const unsigned short* __restrict__ WIT,
    unsigned short* __restrict__ ZXb,
    const unsigned short* __restrict__ WGT, unsigned short* __restrict__ Gb,
    const float* __restrict__ gate_b)
{
  __shared__ alignas(16) unsigned short L[65536];   // 128 KiB
  const int bid = blockIdx.x;
  const int xcd = bid & 7;
  #pragma unroll 1
  for (int t = 0; t < 2; t++) {
    const int within = (bid >> 3) + 32 * t;
    const unsigned short* Btp; unsigned short* Cbp;
    int N_, m0, n0, epi; const float* bias;
    if (within < 52) {
      Btp = WIT; Cbp = ZXb; N_ = DINPROJ; epi = 0; bias = nullptr;
      m0 = (xcd * 4 + (within & 3)) * 256;
      n0 = (within >> 2) * 256;
    } else {
      const int w2 = within - 52;
      Btp = WGT; Cbp = Gb; N_ = DMODEL; epi = 1; bias = gate_b;
      m0 = (xcd * 4 + (w2 & 3)) * 256;
      n0 = (w2 >> 2) * 256;
    }
    gemm256(XN, Btp, Cbp, N_, m0, n0, epi, bias, L);
  }
}

// ============ 128x256 4-PHASE GEMM (512 thr, counted vmcnt(2), param K) ==========
// (R6-proven. 8 waves 2Mx4N of 64x64; LDS 96KiB; counted VW2 keeps 2 loads in
//  flight across every wait; tiles >= NT clamp to k=0 junk, drained at exit.)
__device__ __forceinline__ void gemm512(const unsigned short* __restrict__ A,
    const unsigned short* __restrict__ Bt, float* __restrict__ Cf,
    unsigned short* __restrict__ Cb, int N, int K, int NT, int m0, int n0,
    int epi, const float* __restrict__ bias, const float* __restrict__ resid,
    const unsigned short* __restrict__ gmul, const float* __restrict__ rsc,
    unsigned short* L)
{
  const int tid = threadIdx.x;
  const int lane = tid & 63, w = tid >> 6;
  const int wm2 = w >> 2, wn4 = w & 3;
  const int l15 = lane & 15, lq = lane >> 4;
  const int aswz = l15 & 7;
  const int aoff0 = ((lq)     ^ aswz) * 8;
  const int aoff1 = ((lq + 4) ^ aswz) * 8;
  const int boff  = (lq ^ ((l15 >> 1) & 3)) * 8;
  const int arow = (wm2 * 64 + l15) * 64;          // + mi*1024 + buf*8192 + aoff
  const int brow = 16384 + (wn4 * 64 + l15) * 32;  // + buf*16384 + ks*8192 + ni*512 + boff
  const int w512 = w * 512;

  const int lr3 = lane >> 3, lr2 = lane >> 2;
  const int gqA = ((lane & 7) ^ lr3) * 8;
  const int gqB = ((lane & 3) ^ (lr3 & 3)) * 8;
  const unsigned short* sAlo = A + (size_t)(m0 + 8*w + lr3) * K + gqA;   // rows 0-63
  const unsigned short* sAhi = sAlo + (size_t)64 * K;                    // rows 64-127
  const unsigned short* sB0 = Bt + (size_t)(n0 + 16*w + lr2) * K + gqB;  // rows 0-127
  const unsigned short* sB1 = sB0 + (size_t)128 * K;                     // rows 128-255

  f32x4 acc[4][4];
  #pragma unroll
  for (int i = 0; i < 4; i++)
    #pragma unroll
    for (int jj = 0; jj < 4; jj++) acc[i][jj] = (f32x4){0.f, 0.f, 0.f, 0.f};
  short8 a_[4], bK[4];

  // ---- prologue: tile0 full (6) + tile1 B-k0 (2); keep 2 in flight ----
  gld16(sAlo, &L[w512]); gld16(sAhi, &L[4096 + w512]);
  gld16(sB0, &L[16384 + w512]); gld16(sB1, &L[20480 + w512]);
  gld16(sB0 + 32, &L[24576 + w512]); gld16(sB1 + 32, &L[28672 + w512]);
  gld16(sB0 + 64, &L[32768 + w512]); gld16(sB1 + 64, &L[36864 + w512]);
  VW2();
  FENCE(); __builtin_amdgcn_s_barrier(); FENCE(); __builtin_amdgcn_sched_barrier(0);

  #pragma unroll 1
  for (int j = 0; j < NT/2; j++) {
    const int kO  = (2*j + 1) * 64;
    const int kE2 = (2*j + 2 < NT) ? (2*j + 2) * 64 : 0;
    const int kO2 = (2*j + 3 < NT) ? (2*j + 3) * 64 : 0;

    // ph1: buf0 ks0; stage A-O (buf1) + B-O-k1 (buf1)
    #pragma unroll
    for (int mi = 0; mi < 4; mi++) a_[mi] = lds8(L, arow + mi*1024 + aoff0);
    #pragma unroll
    for (int ni = 0; ni < 4; ni++) bK[ni] = lds8(L, brow + ni*512 + boff);
    gld16(sAlo + kO, &L[8192 + w512]); gld16(sAhi + kO, &L[12288 + w512]);
    gld16(sB0 + kO + 32, &L[40960 + w512]); gld16(sB1 + kO + 32, &L[45056 + w512]);
    BARX(); mfma16t<0>(acc, a_, bK); BARX();
    // ph2: buf0 ks1; stage B-E'-k0 (buf0); WAIT(2)
    #pragma unroll
    for (int mi = 0; mi < 4; mi++) a_[mi] = lds8(L, arow + mi*1024 + aoff1);
    #pragma unroll
    for (int ni = 0; ni < 4; ni++) bK[ni] = lds8(L, brow + 8192 + ni*512 + boff);
    gld16(sB0 + kE2, &L[16384 + w512]); gld16(sB1 + kE2, &L[20480 + w512]);
    BARX(); mfma16t<0>(acc, a_, bK);
    __builtin_amdgcn_sched_barrier(0); VW2(); BARX();
    // ph3: buf1 ks0; stage A-E' (buf0) + B-E'-k1 (buf0)
    #pragma unroll
    for (int mi = 0; mi < 4; mi++) a_[mi] = lds8(L, 8192 + arow + mi*1024 + aoff0);
    #pragma unroll
    for (int ni = 0; ni < 4; ni++) bK[ni] = lds8(L, brow + 16384 + ni*512 + boff);
    gld16(sAlo + kE2, &L[w512]); gld16(sAhi + kE2, &L[4096 + w512]);
    gld16(sB0 + kE2 + 32, &L[24576 + w512]); gld16(sB1 + kE2 + 32, &L[28672 + w512]);
    BARX(); mfma16t<0>(acc, a_, bK); BARX();
    // ph4: buf1 ks1; stage B-O'-k0 (buf1); WAIT(2)
    #pragma unroll
    for (int mi = 0; mi < 4; mi++) a_[mi] = lds8(L, 8192 + arow + mi*1024 + aoff1);
    #pragma unroll
    for (int ni = 0; ni < 4; ni++) bK[ni] = lds8(L, brow + 16384 + 8192 + ni*512 + boff);
    gld16(sB0 + kO2, &L[32768 + w512]); gld16(sB1 + kO2, &L[36864 + w512]);
    BARX(); mfma16t<0>(acc, a_, bK);
    __builtin_amdgcn_sched_barrier(0); VW2(); BARX();
  }
  asm volatile("s_waitcnt vmcnt(0)" ::: "memory");

  // ---- epilogue: lane holds cols (ncb+16ni .. +3) of row (mrow+16mi) ----
  const int mrowb = m0 + wm2 * 64 + l15;
  const int ncb   = n0 + wn4 * 64 + 4 * lq;
  if (epi == 3) {           // RMS rsqrt(row) * gate -> bf16
    #pragma unroll
    for (int mi = 0; mi < 4; mi++) {
      const int row = mrowb + 16*mi;
      const float sc = rsqrtf(rsc[row] * (1.f / DINNER) + EPSF);
      unsigned short* Crow = Cb + (size_t)row * N + ncb;
      const unsigned short* Grow = gmul + (size_t)row * N + ncb;
      #pragma unroll
      for (int ni = 0; ni < 4; ni++) {
        f32x4 v = acc[mi][ni];
        ull gv = *(const ull*)(Grow + 16*ni);
        *(ull*)(Crow + 16*ni) = pack4bf(
            v[0] * sc * bf2f((unsigned short)(gv)),
            v[1] * sc * bf2f((unsigned short)(gv >> 16)),
            v[2] * sc * bf2f((unsigned short)(gv >> 32)),
            v[3] * sc * bf2f((unsigned short)(gv >> 48)));
      }
    }
  } else {                  // epi==2: C + bias[n] + resid[m][n] -> f32 out
    f32x4 bb[4];
    #pragma unroll
    for (int ni = 0; ni < 4; ni++) bb[ni] = *(const f32x4*)(bias + ncb + 16*ni);
    #pragma unroll
    for (int mi = 0; mi < 4; mi++) {
      const int row = mrowb + 16*mi;
      float* Co = Cf + (size_t)row * N + ncb;
      const float* Rr = resid + (size_t)row * N + ncb;
      #pragma unroll
      for (int ni = 0; ni < 4; ni++) {
        f32x4 v = acc[mi][ni];
        f32x4 rv = *(const f32x4*)(Rr + 16*ni);
        f32x4 o = { v[0] + bb[ni][0] + rv[0], v[1] + bb[ni][1] + rv[1],
                    v[2] + bb[ni][2] + rv[2], v[3] + bb[ni][3] + rv[3] };
        *(f32x4*)(Co + 16*ni) = o;
      }
    }
  }
}

// grid 192 = 8 xcd x 8 m-slots x 3 n; A's 3 n-tiles land on the same XCD (L2-hot A).
__global__ __launch_bounds__(512, 2) void k_gemm512(const unsigned short* __restrict__ A,
    const unsigned short* __restrict__ Bt, float* __restrict__ Cf,
    unsigned short* __restrict__ Cb, int N, int K, int NT, int epi,
    const float* __restrict__ bias, const float* __restrict__ resid,
    const unsigned short* __restrict__ gmul, const float* __restrict__ rsc)
{
  __shared__ alignas(16) unsigned short L[49152];   // 96 KiB
  const int bid = blockIdx.x;
  const int xcd = bid & 7, within = bid >> 3;       // 0..23
  const int m0 = (xcd * 8 + (within & 7)) * 128;
  const int n0 = (within >> 3) * 256;
  gemm512(A, Bt, Cf, Cb, N, K, NT, m0, n0, epi, bias, resid, gmul, rsc, L);
}

// ---------------- LDS-tiled causal conv1d (K=4) + SiLU (R2-proven) ---------------
__global__ __launch_bounds__(256) void k_conv(const unsigned short* __restrict__ zx,
    const float* __restrict__ cw, const float* __restrict__ cb,
    unsigned short* __restrict__ out)
{
  __shared__ alignas(8) unsigned short tile[67][132];   // pitch 264 B
  const int tid = threadIdx.x;
  const int c0 = blockIdx.x * 128;          // 13 tiles x 128 = 1664 = CONVD
  const int tc = blockIdx.y;                // 128 token-chunks of 64
  const int t0 = tc * 64;
  const bool haloOK = (tc & 63) != 0;       // chunk 0 of each batch has no halo
  for (int i = tid; i < 67 * 16; i += 256) {
    int row = i >> 4, g = i & 15;
    ull v0 = 0, v1 = 0;
    if (row >= 3 || haloOK) {
      const unsigned short* p = zx + (size_t)(t0 - 3 + row) * DINPROJ + DINNER + c0 + g * 8;
      v0 = *(const ull*)p;
      v1 = *(const ull*)(p + 4);
    }
    *(ull*)(&tile[row][g * 8])     = v0;
    *(ull*)(&tile[row][g * 8 + 4]) = v1;
  }
  __syncthreads();
  const int ch0 = (tid & 63) * 2;           // 0..126
  const int trow = tid >> 6;                // 0..3
  const int cg = c0 + ch0;
  float cw0[4], cw1[4];
  #pragma unroll
  for (int k = 0; k < 4; k++) { cw0[k] = cw[cg * 4 + k]; cw1[k] = cw[(cg + 1) * 4 + k]; }
  const float cb0 = cb[cg], cb1 = cb[cg + 1];
  #pragma unroll
  for (int q = 0; q < 16; q++) {
    int tq = trow * 16 + q;
    float a0 = cb0, a1 = cb1;
    #pragma unroll
    for (int k = 0; k < 4; k++) {
      unsigned int u = *(const unsigned int*)(&tile[tq + k][ch0]);
      a0 += bf2f((unsigned short)u) * cw0[k];
      a1 += bf2f((unsigned short)(u >> 16)) * cw1[k];
    }
    float s0 = a0 * sigm(a0), s1 = a1 * sigm(a1);
    *(unsigned int*)(out + (size_t)(t0 + tq) * CONVD + cg) =
        (unsigned int)f2bf(s0) | ((unsigned int)f2bf(s1) << 16);
  }
}

// ---------------- SSD pass 1 (MFMA): S[bh,c][n][p] (bf16) (R2-proven) ------------
__global__ __launch_bounds__(256) void k_chunkstate(const unsigned short* __restrict__ zx,
    const unsigned short* __restrict__ xbcc, const float* __restrict__ dt_bias,
    const float* __restrict__ A_log, unsigned short* __restrict__ S, float* __restrict__ CD)
{
  const int c = blockIdx.x, bh = blockIdx.y;
  const int b = bh / NH, h = bh % NH;
  const int tid = threadIdx.x;
  const int lane = tid & 63, w = tid >> 6;
  const int l15 = lane & 15, lq = lane >> 4;
  __shared__ float wv_[64];
  __shared__ alignas(16) unsigned short Bwt[64][LP];  // [n][s]
  __shared__ alignas(16) unsigned short Xt [64][LP];  // [p][s]

  if (tid < 64) {                     // wave 0: dt, prefix-scan of Lc
    int t = c * 64 + tid;
    float xx = bf2f(zx[((size_t)(b * SEQ + t)) * DINPROJ + (DINNER + CONVD) + h]) + dt_bias[h];
    float dt_ = (xx > 15.f) ? xx : log1pf(__expf(xx));
    float Ah = -__expf(A_log[h]);
    float v = dt_ * Ah;
    #pragma unroll
    for (int off = 1; off < 64; off <<= 1) {
      float u = __shfl_up(v, off);
      if (tid >= off) v += u;
    }
    float L63 = __shfl(v, 63);
    wv_[tid] = __expf(L63 - v) * dt_;
    if (tid == 63) CD[bh * 64 + c] = __expf(v);
  }
  ull braw[4];
  #pragma unroll
  for (int it = 0; it < 4; it++) {
    int i4 = tid + 256 * it;
    int s = i4 >> 4, q4 = (i4 & 15) * 4;
    size_t rb = ((size_t)(b * SEQ) + c * 64 + s) * CONVD;
    braw[it] = *(const ull*)(xbcc + rb + DINNER + q4);
    unsigned short xs[4];
    *(ull*)xs = *(const ull*)(xbcc + rb + h * HD + q4);
    Xt[q4+0][s] = xs[0]; Xt[q4+1][s] = xs[1]; Xt[q4+2][s] = xs[2]; Xt[q4+3][s] = xs[3];
  }
  __syncthreads();
  #pragma unroll
  for (int it = 0; it < 4; it++) {
    int i4 = tid + 256 * it;
    int s = i4 >> 4, q4 = (i4 & 15) * 4;
    float wsc = wv_[s];
    unsigned short us[4];
    *(ull*)us = braw[it];
    Bwt[q4+0][s] = f2bf(bf2f(us[0]) * wsc);
    Bwt[q4+1][s] = f2bf(bf2f(us[1]) * wsc);
    Bwt[q4+2][s] = f2bf(bf2f(us[2]) * wsc);
    Bwt[q4+3][s] = f2bf(bf2f(us[3]) * wsc);
  }
  __syncthreads();
  const int n0 = 16 * w;
  short8 a0 = *(const short8*)(&Bwt[n0 + l15][lq * 8]);
  short8 a1 = *(const short8*)(&Bwt[n0 + l15][32 + lq * 8]);
  size_t sb = ((size_t)bh * 64 + c) * 4096;
  #pragma unroll
  for (int pt = 0; pt < 4; pt++) {
    f32x4 acc = (f32x4){0.f, 0.f, 0.f, 0.f};
    short8 b0 = *(const short8*)(&Xt[16*pt + l15][lq * 8]);
    short8 b1 = *(const short8*)(&Xt[16*pt + l15][32 + lq * 8]);
    acc = __builtin_amdgcn_mfma_f32_16x16x32_bf16(a0, b0, acc, 0, 0, 0);
    acc = __builtin_amdgcn_mfma_f32_16x16x32_bf16(a1, b1, acc, 0, 0, 0);
    #pragma unroll
    for (int r = 0; r < 4; r++) {
      int n = n0 + 4*lq + r, p = 16*pt + l15;
      S[sb + (size_t)n * 64 + p] = f2bf(acc[r]);
    }
  }
}

// ---------------- SSD pass 2: chunk recurrence (16-batched prefetch) -------------
// Same arithmetic order as R2 (bit-identical); 16-wide batching halves the number
// of dependent L3-latency rounds (4 instead of 8).
__global__ __launch_bounds__(256) void k_chunkrec(unsigned short* __restrict__ S,
    const float* __restrict__ CD)
{
  const int bh = blockIdx.x >> 4, part = blockIdx.x & 15;
  const int e = part * 256 + threadIdx.x;
  float g = 0.f;
  size_t base = (size_t)bh * 64 * 4096 + e;
  const float* cdp = CD + bh * 64;
  #pragma unroll 1
  for (int cb2 = 0; cb2 < 64; cb2 += 16) {
    unsigned short sv[16];
    #pragma unroll
    for (int u = 0; u < 16; u++) sv[u] = S[base + (size_t)(cb2 + u) * 4096];
    #pragma unroll
    for (int u = 0; u < 16; u++) {
      float s = bf2f(sv[u]);
      S[base + (size_t)(cb2 + u) * 4096] = f2bf(g);   // slot c now holds G_c
      g = cdp[cb2 + u] * g + s;
    }
  }
}

// ---------------- SSD pass 3 (MFMA): y*silu(z) fused, ssq atomics ----------------
// B/C staging VECTORIZED (ull global load + ull LDS store; both 8B-aligned:
// CONVD*2=3328 and LP*2=144 are multiples of 8). Xt/Gt remain scalar (transposed
// scatter is required by the MFMA fragment layout).
__global__ __launch_bounds__(256) void k_chunkout(const unsigned short* __restrict__ zx,
    const unsigned short* __restrict__ xbcc, const unsigned short* __restrict__ S,
    const float* __restrict__ dt_bias, const float* __restrict__ A_log,
    const float* __restrict__ Dp, unsigned short* __restrict__ Y,
    float* __restrict__ ssq)
{
  const int c = blockIdx.x, bh = blockIdx.y;
  const int b = bh / NH, h = bh % NH;
  const int tid = threadIdx.x;
  const int lane = tid & 63, w = tid >> 6;
  const int l15 = lane & 15, lq = lane >> 4;
  __shared__ float dts[64], Lc[64], ein[64];
  __shared__ alignas(16) unsigned short Cs  [64][LP];  // [i][n]
  __shared__ alignas(16) unsigned short BsPs[64][LP];  // [s][n], then P[i][s]
  __shared__ alignas(16) unsigned short Xt  [64][LP];  // [p][s]
  __shared__ alignas(16) unsigned short Gt  [64][LP];  // [p][n]

  if (tid < 64) {                     // wave 0: dt, prefix-scan of Lc
    int t = c * 64 + tid;
    float xx = bf2f(zx[((size_t)(b * SEQ + t)) * DINPROJ + (DINNER + CONVD) + h]) + dt_bias[h];
    float dt_ = (xx > 15.f) ? xx : log1pf(__expf(xx));
    dts[tid] = dt_;
    float Ah = -__expf(A_log[h]);
    float v = dt_ * Ah;
    #pragma unroll
    for (int off = 1; off < 64; off <<= 1) {
      float u = __shfl_up(v, off);
      if (tid >= off) v += u;
    }
    Lc[tid] = v;
    ein[tid] = __expf(v);
  }
  const size_t gslot = ((size_t)bh * 64 + c) * 4096;
  #pragma unroll
  for (int it = 0; it < 4; it++) {
    int i4 = tid + 256 * it;
    int rr = i4 >> 4, q4 = (i4 & 15) * 4;
    size_t rb = ((size_t)(b * SEQ) + c * 64 + rr) * CONVD;
    *(ull*)&Cs[rr][q4]   = *(const ull*)(xbcc + rb + (DINNER + DSTATE) + q4);
    *(ull*)&BsPs[rr][q4] = *(const ull*)(xbcc + rb + DINNER + q4);
    unsigned short xs[4];
    *(ull*)xs = *(const ull*)(xbcc + rb + h * HD + q4);
    Xt[q4+0][rr] = xs[0]; Xt[q4+1][rr] = xs[1]; Xt[q4+2][rr] = xs[2]; Xt[q4+3][rr] = xs[3];
    unsigned short gs[4];
    *(ull*)gs = *(const ull*)(S + gslot + (size_t)i4 * 4);
    Gt[q4+0][rr] = gs[0]; Gt[q4+1][rr] = gs[1]; Gt[q4+2][rr] = gs[2]; Gt[q4+3][rr] = gs[3];
  }
  __syncthreads();
  // ---- matmul1: G[i][s] = sum_n C[i][n] B[s][n]; apply causal decay mask -> P ----
  const int i0 = 16 * w;
  short8 ac0 = *(const short8*)(&Cs[i0 + l15][lq * 8]);
  short8 ac1 = *(const short8*)(&Cs[i0 + l15][32 + lq * 8]);
  float pp[4][4];
  #pragma unroll
  for (int st = 0; st < 4; st++) {
    f32x4 g = (f32x4){0.f, 0.f, 0.f, 0.f};
    if (st <= w) {                                   // wave-uniform causal skip
      short8 b0 = *(const short8*)(&BsPs[16*st + l15][lq * 8]);
      short8 b1 = *(const short8*)(&BsPs[16*st + l15][32 + lq * 8]);
      g = __builtin_amdgcn_mfma_f32_16x16x32_bf16(ac0, b0, g, 0, 0, 0);
      g = __builtin_amdgcn_mfma_f32_16x16x32_bf16(ac1, b1, g, 0, 0, 0);
    }
    #pragma unroll
    for (int r = 0; r < 4; r++) {
      int i = i0 + 4*lq + r, s = 16*st + l15;
      pp[st][r] = (s <= i) ? g[r] * __expf(Lc[i] - Lc[s]) * dts[s] : 0.f;
    }
  }
  __syncthreads();                                   // all waves done reading Bs
  #pragma unroll
  for (int st = 0; st < 4; st++)
    #pragma unroll
    for (int r = 0; r < 4; r++)
      BsPs[i0 + 4*lq + r][16*st + l15] = f2bf(pp[st][r]);   // P[i][s], s contiguous
  __syncthreads();
  // ---- matmul2+3: Y[i][p] = (P@X + ein[i]*(C@G) + D*x) * silu(z) ----
  short8 ap0 = *(const short8*)(&BsPs[i0 + l15][lq * 8]);
  short8 ap1 = *(const short8*)(&BsPs[i0 + l15][32 + lq * 8]);
  const float Dh = Dp[h];
  float sq[4] = {0.f, 0.f, 0.f, 0.f};
  #pragma unroll
  for (int pt = 0; pt < 4; pt++) {
    const int p0 = 16 * pt;
    f32x4 y1 = (f32x4){0.f, 0.f, 0.f, 0.f};
    f32x4 y2 = (f32x4){0.f, 0.f, 0.f, 0.f};
    short8 bx0 = *(const short8*)(&Xt[p0 + l15][lq * 8]);
    y1 = __builtin_amdgcn_mfma_f32_16x16x32_bf16(ap0, bx0, y1, 0, 0, 0);
    if (w >= 2) {                                    // P rows of wave w have k < 16(w+1)
      short8 bx1 = *(const short8*)(&Xt[p0 + l15][32 + lq * 8]);
      y1 = __builtin_amdgcn_mfma_f32_16x16x32_bf16(ap1, bx1, y1, 0, 0, 0);
    }
    short8 bg0 = *(const short8*)(&Gt[p0 + l15][lq * 8]);
    short8 bg1 = *(const short8*)(&Gt[p0 + l15][32 + lq * 8]);
    y2 = __builtin_amdgcn_mfma_f32_16x16x32_bf16(ac0, bg0, y2, 0, 0, 0);
    y2 = __builtin_amdgcn_mfma_f32_16x16x32_bf16(ac1, bg1, y2, 0, 0, 0);
    #pragma unroll
    for (int r = 0; r < 4; r++) {
      int i = i0 + 4*lq + r, p = p0 + l15;
      float xv = bf2f(Xt[p][i]);
      float o = y1[r] + ein[i] * y2[r] + Dh * xv;
      size_t row = (size_t)(b * SEQ) + c * 64 + i;
      float zv = bf2f(zx[row * DINPROJ + h * HD + p]);
      float og = o * (zv * sigm(zv));
      Y[row * DINNER + h * HD + p] = f2bf(og);
      sq[r] += og * og;
    }
  }
  // per-row sum of squares: reduce over the 16 l15 lanes, 1 atomic/row
  #pragma unroll
  for (int r = 0; r < 4; r++) {
    float s = sq[r];
    s += __shfl_xor(s, 1); s += __shfl_xor(s, 2);
    s += __shfl_xor(s, 4); s += __shfl_xor(s, 8);
    if (l15 == 0)
      atomicAdd(ssq + (size_t)(b * SEQ) + c * 64 + (i0 + 4*lq + r), s);
  }
}

// ---------------- launch ----------------------------------------------------------
extern "C" void kernel_launch(void* const* d_in, const int* in_sizes, int n_in,
                              void* d_out, int out_size, void* d_ws, size_t ws_size,
                              hipStream_t stream)
{
  const float* x         = (const float*)d_in[0];
  const float* ln_w      = (const float*)d_in[1];
  const float* ln_b      = (const float*)d_in[2];
  const float* in_proj_w = (const float*)d_in[3];
  const float* conv_w    = (const float*)d_in[4];
  const float* conv_b    = (const float*)d_in[5];
  const float* dt_bias   = (const float*)d_in[6];
  const float* A_log     = (const float*)d_in[7];
  const float* D_param   = (const float*)d_in[8];
  const float* rms_w     = (const float*)d_in[9];
  const float* out_proj_w= (const float*)d_in[10];
  const float* gate_w    = (const float*)d_in[11];
  const float* gate_b    = (const float*)d_in[12];
  const float* out_w     = (const float*)d_in[13];
  const float* out_b     = (const float*)d_in[14];
  float* out = (float*)d_out;
  char* ws = (char*)d_ws;

  // ---- workspace layout (bytes). peak = 177,848,320 B (~170 MB) — R2 layout ----
  const size_t WS_NEEDED = 177848320ull;
  if (ws_size < WS_NEEDED) return;

  unsigned short* XN    = (unsigned short*)(ws + 0);
  unsigned short* WIT   = (unsigned short*)(ws + 12582912);
  unsigned short* WGT   = (unsigned short*)(ws + 17534976);
  unsigned short* WOPT  = (unsigned short*)(ws + 18714624);
  unsigned short* WOT   = (unsigned short*)(ws + 21073920);
  unsigned short* ZXb   = (unsigned short*)(ws + 22253568);   // 8192x3224 bf16
  unsigned short* XBCCb = (unsigned short*)(ws + 75075584);   // 8192x1664 bf16
  unsigned short* Sb    = (unsigned short*)(ws + 102338560);  // 3072x4096 bf16 (25.2MB)
  unsigned short* Gb    = (unsigned short*)(ws + 127504384);  // 8192x768 bf16 (gate out)
  float*          ssq   = (float*)(ws + 140087296);           // 8192 f32 row sum-sq
  float*          CD    = (float*)(ws + 152670208);           // 3072 f32
  unsigned short* Yb    = (unsigned short*)(ws + 152682496);  // 8192x1536 bf16 (y*silu(z))
  // overlay:
  unsigned short* YG    = (unsigned short*)(ws + 75075584);   // in XBCCb region (dead after chunkout)

  // 1) merged prep: LN (8192) + 4 weight transposes (4728) + ssq zero
  k_prep<<<NTOK + 4728, 256, 0, stream>>>(x, ln_w, ln_b, XN, ssq,
                                          in_proj_w, WIT, gate_w, WGT,
                                          out_proj_w, WOPT, out_w, WOT, rms_w);
  // 2) in_proj + gate GEMMs: 256 persistent blocks x 2 static tiles (R2 mapping)
  k_ipg256<<<256, 512, 0, stream>>>(XN, WIT, ZXb, WGT, Gb, gate_b);
  // 3) LDS-tiled causal conv + silu (bf16 -> bf16)
  k_conv<<<dim3(13, 128), 256, 0, stream>>>(ZXb, conv_w, conv_b, XBCCb);
  // 4-6) SSD scan (S in bf16; chunkout fuses y*silu(z) + ssq)
  k_chunkstate<<<dim3(NCHUNK, BSZ * NH), 256, 0, stream>>>(ZXb, XBCCb, dt_bias, A_log, Sb, CD);
  k_chunkrec<<<BSZ * NH * 16, 256, 0, stream>>>(Sb, CD);
  k_chunkout<<<dim3(NCHUNK, BSZ * NH), 256, 0, stream>>>(ZXb, XBCCb, Sb, dt_bias, A_log,
                                                         D_param, Yb, ssq);
  // 7) out_proj GEMM (128x256 4-phase core): RMS rsqrt * gate epilogue -> YG bf16
  k_gemm512<<<192, 512, 0, stream>>>(Yb, WOPT, nullptr, YG, DMODEL, DINNER, 24, 3,
                                     nullptr, nullptr, Gb, ssq);
  // 8) final GEMM (128x256 4-phase core): + bias + residual -> f32 d_out
  k_gemm512<<<192, 512, 0, stream>>>(YG, WOT, out, nullptr, DMODEL, DMODEL, 12, 2,
                                     out_b, x, nullptr, nullptr);
}

// Round 8
// 308.079 us; speedup vs baseline: 1.0106x; 1.0106x over previous
//
#include <hip/hip_runtime.h>
#include <hip/hip_bf16.h>
#include <cstddef>

// ---------------- problem constants ----------------
#define DMODEL  768
#define DINNER  1536
#define DSTATE  64
#define NH      24
#define HD      64
#define CONVD   1664      // DINNER + 2*DSTATE
#define DINPROJ 3224      // 2*DINNER + 2*DSTATE + NH
#define SEQ     4096
#define BSZ     2
#define NTOK    8192      // BSZ*SEQ
#define NCHUNK  64        // SEQ/64
#define EPSF    1e-5f
#define LP      72        // LDS pitch (shorts) for SSD kernels

typedef __attribute__((ext_vector_type(8))) short  short8;
typedef __attribute__((ext_vector_type(4))) float  f32x4;
typedef unsigned long long ull;

// ---------------- helpers ----------------
__device__ __forceinline__ unsigned short f2bf(float f) {
  union { float f; unsigned int u; } v; v.f = f;
  unsigned int r = v.u + 0x7fffu + ((v.u >> 16) & 1u);   // RNE
  return (unsigned short)(r >> 16);
}
__device__ __forceinline__ float bf2f(unsigned short u) {
  union { unsigned int i; float f; } v; v.i = ((unsigned int)u) << 16; return v.f;
}
__device__ __forceinline__ ull pack4bf(float a, float b, float c, float d) {
  return (ull)(f2bf(a) | ((unsigned int)f2bf(b) << 16))
       | ((ull)(f2bf(c) | ((unsigned int)f2bf(d) << 16)) << 32);
}
__device__ __forceinline__ float sigm(float x) { return 1.f / (1.f + __expf(-x)); }

// async 16B global -> LDS (lane i of the wave lands at ldsbase + i*16)
__device__ __forceinline__ void gld16(const unsigned short* g, unsigned short* l) {
  __builtin_amdgcn_global_load_lds(
      (const __attribute__((address_space(1))) unsigned int*)g,
      (__attribute__((address_space(3))) unsigned int*)l, 16, 0, 0);
}

// ---------------- merged prep: LayerNorm (ids 0..8191) + 4 weight transposes ------
__global__ __launch_bounds__(256) void k_prep(const float* __restrict__ x,
    const float* __restrict__ lw, const float* __restrict__ lb,
    unsigned short* __restrict__ xn, float* __restrict__ ssq,
    const float* __restrict__ W0, unsigned short* __restrict__ T0,
    const float* __restrict__ W1, unsigned short* __restrict__ T1,
    const float* __restrict__ W2, unsigned short* __restrict__ T2,
    const float* __restrict__ W3, unsigned short* __restrict__ T3,
    const float* __restrict__ rmsw)
{
  const int id = blockIdx.x, tid = threadIdx.x;
  if (id < NTOK) {
    __shared__ float red[4];
    if (id < 32) ssq[id * 256 + tid] = 0.f;          // 8192 f32 = 32x256
    const float* xr = x + (size_t)id * DMODEL;
    float v[3]; float s = 0.f;
    #pragma unroll
    for (int q = 0; q < 3; q++) { v[q] = xr[q*256 + tid]; s += v[q]; }
    #pragma unroll
    for (int off = 32; off; off >>= 1) s += __shfl_down(s, off);
    if ((tid & 63) == 0) red[tid >> 6] = s;
    __syncthreads();
    const float mu = (red[0] + red[1] + red[2] + red[3]) * (1.f / DMODEL);
    __syncthreads();
    float s2 = 0.f;
    #pragma unroll
    for (int q = 0; q < 3; q++) { float d = v[q] - mu; s2 += d * d; }
    #pragma unroll
    for (int off = 32; off; off >>= 1) s2 += __shfl_down(s2, off);
    if ((tid & 63) == 0) red[tid >> 6] = s2;
    __syncthreads();
    const float rs = rsqrtf((red[0] + red[1] + red[2] + red[3]) * (1.f / DMODEL) + EPSF);
    unsigned short* xo = xn + (size_t)id * DMODEL;
    #pragma unroll
    for (int q = 0; q < 3; q++) {
      int col = q*256 + tid;
      xo[col] = f2bf((v[q] - mu) * rs * lw[col] + lb[col]);
    }
  } else {
    int wt = id - NTOK;
    const float* W; unsigned short* T; int K, N, nt; const float* scale = nullptr;
    if (wt < 2424)      { W = W0; T = T0; K = 768;  N = 3224; nt = 101; }
    else if (wt < 3000) { W = W1; T = T1; K = 768;  N = 768;  nt = 24; wt -= 2424; }
    else if (wt < 4152) { W = W2; T = T2; K = 1536; N = 768;  nt = 24; wt -= 3000; scale = rmsw; }
    else                { W = W3; T = T3; K = 768;  N = 768;  nt = 24; wt -= 4152; }
    const int n0 = (wt % nt) * 32, k0 = (wt / nt) * 32;
    __shared__ float tile[32][33];
    const int tx = tid & 31, ty = tid >> 5;           // 32 x 8
    #pragma unroll
    for (int r = 0; r < 4; r++) {
      int k = k0 + ty + 8*r;
      if (k < K && n0 + tx < N) tile[ty + 8*r][tx] = W[(size_t)k * N + n0 + tx];
    }
    __syncthreads();
    #pragma unroll
    for (int r = 0; r < 4; r++) {
      int n = n0 + ty + 8*r, k = k0 + tx;
      if (n < N && k < K) {
        float v = tile[tx][ty + 8*r];
        if (scale) v *= scale[k];
        T[(size_t)n * K + k] = f2bf(v);
      }
    }
  }
}

// ---------------- shared GEMM helpers ----------------
template<int MIB, int NACC>
__device__ __forceinline__ void mfma16t(f32x4 (&acc)[NACC][4], const short8 (&a_)[4],
                                        const short8 (&bK)[4]) {
  __builtin_amdgcn_s_setprio(1);
  #pragma unroll
  for (int mi = 0; mi < 4; mi++)
    #pragma unroll
    for (int ni = 0; ni < 4; ni++)
      acc[MIB + mi][ni] =
          __builtin_amdgcn_mfma_f32_16x16x32_bf16(bK[ni], a_[mi], acc[MIB + mi][ni], 0, 0, 0);
  __builtin_amdgcn_s_setprio(0);
}

__device__ __forceinline__ short8 lds8(const unsigned short* L, int off) {
  return *(const short8*)(&L[off]);
}

#define FENCE() asm volatile("" ::: "memory")
#define BARX() do { __builtin_amdgcn_sched_barrier(0); FENCE(); \
  __builtin_amdgcn_s_barrier(); FENCE(); __builtin_amdgcn_sched_barrier(0); } while (0)
#define VW2() asm volatile("s_waitcnt vmcnt(2)" ::: "memory")

// ================= 256x256 4-PHASE GEMM core (K=768 fixed) =======================
// R8: merged phases (was 8-phase, R2). 512 thr = 8 waves 2Mx4N; LDS 128 KiB;
// swapped MFMA -> lane holds 4 consecutive columns. Per iteration (2 K-tiles,
// E=2j buf0 read mph1-2, O=2j+1 buf1 read mph3-4), each phase runs TWO 16-MFMA
// clusters (mi0-3 then mi4-7, no barrier between; compiler lgkmcnt covers the
// second PH_LDA). Stage placement (WAR: target slot's last ds_read >=1 barrier
// earlier; phase reads opposite buffer or different k-slot):
//   mph1: A-O x4 + B-O-k1 x2 (->buf1; phase reads buf0)
//   mph2: B-E'-k0 x2 (buf0 k0 last read mph1)                 [vmcnt(2)]
//   mph3: B-E'-k1 x2 + A-E' x4 (->buf0; phase reads buf1)
//   mph4: B-O'-k0 x2 (buf1 k0 last read mph3)                 [vmcnt(2)]
// In-flight: enter mph1 with 2 (B-O-k0); mph1 +6=8; mph2 +2=10, vmcnt(2)
// retires {B-O-k0,A-O,B-O-k1}=8 -> tile O landed before mph3; mph3 +6=8;
// mph4 +2=10, vmcnt(2) retires {B-E'-k0,B-E'-k1,A-E'}=8 -> tile E' landed.
// MFMA accumulation order identical to the 8-phase version (bit-identical acc).
// Peeled tail (tiles 10/11) drains at t-mph2 -> vmcnt clean at exit.
#define PH_LDA(BUF, MIBASE, AOFF) do { \
  a_[0] = lds8(L, (BUF) + arow + ((MIBASE)+0)*1024 + (AOFF)); \
  a_[1] = lds8(L, (BUF) + arow + ((MIBASE)+1)*1024 + (AOFF)); \
  a_[2] = lds8(L, (BUF) + arow + ((MIBASE)+2)*1024 + (AOFF)); \
  a_[3] = lds8(L, (BUF) + arow + ((MIBASE)+3)*1024 + (AOFF)); } while (0)

#define PH_LDB(BUF, KS) do { \
  bK[0] = lds8(L, brow + (BUF) + (KS)*8192 + 0*512 + boff); \
  bK[1] = lds8(L, brow + (BUF) + (KS)*8192 + 1*512 + boff); \
  bK[2] = lds8(L, brow + (BUF) + (KS)*8192 + 2*512 + boff); \
  bK[3] = lds8(L, brow + (BUF) + (KS)*8192 + 3*512 + boff); } while (0)

__device__ __forceinline__ void gemm256(const unsigned short* __restrict__ A,
    const unsigned short* __restrict__ Bt, unsigned short* __restrict__ Cb,
    int N, int m0, int n0, int epi, const float* __restrict__ bias,
    unsigned short* L)
{
  const int K = 768;                       // 12 K-tiles: j=0..4 full + peeled tail
  const int tid = threadIdx.x;
  const int lane = tid & 63, w = tid >> 6;
  const int wm2 = w >> 2, wn4 = w & 3;
  const int l15 = lane & 15, lq = lane >> 4;
  const int aoff0 = ((lq)     ^ (l15 & 7)) * 8;
  const int aoff1 = ((lq + 4) ^ (l15 & 7)) * 8;
  const int boff  = (lq ^ ((l15 >> 1) & 3)) * 8;
  const int arow = (wm2 * 128 + l15) * 64;
  const int brow = 32768 + (wn4 * 64 + l15) * 32;

  const int lr3 = lane >> 3, lr2 = lane >> 2;
  const int gqA = ((lane & 7) ^ lr3) * 8;
  const int gqB = ((lane & 3) ^ (lr3 & 3)) * 8;
  const unsigned short* sA0 = A + (size_t)(m0 + 8*w + lr3) * K + gqA;
  const unsigned short* sA1 = sA0 + (size_t)128 * K;
  const unsigned short* sA2 = sA0 + (size_t)64  * K;
  const unsigned short* sA3 = sA0 + (size_t)192 * K;
  int rb0 = n0 + 16*w + lr2;        if (rb0 > N - 1) rb0 = N - 1;
  int rb1 = n0 + 128 + 16*w + lr2;  if (rb1 > N - 1) rb1 = N - 1;
  const unsigned short* sB0 = Bt + (size_t)rb0 * K + gqB;
  const unsigned short* sB1 = Bt + (size_t)rb1 * K + gqB;

  const int dA0 = w*512, dA1 = (16+w)*512, dA2 = (8+w)*512, dA3 = (24+w)*512;
  const int dB0 = 32768 + w*512, dB1 = 32768 + (8+w)*512;

  f32x4 acc[8][4];
  #pragma unroll
  for (int i = 0; i < 8; i++)
    #pragma unroll
    for (int jj = 0; jj < 4; jj++) acc[i][jj] = (f32x4){0.f, 0.f, 0.f, 0.f};
  short8 bK[4];

  // ---- prologue: tile0 full (8) + tile1 B-k0 (2); vmcnt(2) -> 2 in flight ----
  gld16(sA0, &L[dA0]); gld16(sA1, &L[dA1]);
  gld16(sA2, &L[dA2]); gld16(sA3, &L[dA3]);
  gld16(sB0, &L[dB0]); gld16(sB1, &L[dB1]);
  gld16(sB0 + 32, &L[dB0 + 8192]); gld16(sB1 + 32, &L[dB1 + 8192]);
  gld16(sB0 + 64, &L[dB0 + 16384]); gld16(sB1 + 64, &L[dB1 + 16384]);
  VW2();
  FENCE(); __builtin_amdgcn_s_barrier(); FENCE(); __builtin_amdgcn_sched_barrier(0);

  #pragma unroll 1
  for (int j = 0; j < 5; j++) {
    const int kO1 = (2*j + 1) * 64;
    const int kE  = (2*j + 2) * 64;
    const int kO3 = (2*j + 3) * 64;
    short8 a_[4];

    // mph1: buf0 ks0 (mi0-7); stage A-O x4 + B-O-k1 x2 (all -> buf1)
    PH_LDA(0, 0, aoff0); PH_LDB(0, 0);
    gld16(sA0 + kO1, &L[dA0 + 16384]); gld16(sA1 + kO1, &L[dA1 + 16384]);
    gld16(sA2 + kO1, &L[dA2 + 16384]); gld16(sA3 + kO1, &L[dA3 + 16384]);
    gld16(sB0 + kO1 + 32, &L[dB0 + 16384 + 8192]); gld16(sB1 + kO1 + 32, &L[dB1 + 16384 + 8192]);
    BARX(); mfma16t<0>(acc, a_, bK);
    PH_LDA(0, 4, aoff0); mfma16t<4>(acc, a_, bK); BARX();

    // mph2: buf0 ks1; stage B-E'-k0 x2; WAIT vmcnt(2)
    PH_LDA(0, 0, aoff1); PH_LDB(0, 1);
    gld16(sB0 + kE, &L[dB0]); gld16(sB1 + kE, &L[dB1]);
    BARX(); mfma16t<0>(acc, a_, bK);
    PH_LDA(0, 4, aoff1); mfma16t<4>(acc, a_, bK);
    __builtin_amdgcn_sched_barrier(0); VW2(); BARX();

    // mph3: buf1 ks0; stage B-E'-k1 x2 + A-E' x4 (all -> buf0)
    PH_LDA(16384, 0, aoff0); PH_LDB(16384, 0);
    gld16(sB0 + kE + 32, &L[dB0 + 8192]); gld16(sB1 + kE + 32, &L[dB1 + 8192]);
    gld16(sA0 + kE, &L[dA0]); gld16(sA1 + kE, &L[dA1]);
    gld16(sA2 + kE, &L[dA2]); gld16(sA3 + kE, &L[dA3]);
    BARX(); mfma16t<0>(acc, a_, bK);
    PH_LDA(16384, 4, aoff0); mfma16t<4>(acc, a_, bK); BARX();

    // mph4: buf1 ks1; stage B-O'-k0 x2; WAIT vmcnt(2)
    PH_LDA(16384, 0, aoff1); PH_LDB(16384, 1);
    gld16(sB0 + kO3, &L[dB0 + 16384]); gld16(sB1 + kO3, &L[dB1 + 16384]);
    BARX(); mfma16t<0>(acc, a_, bK);
    PH_LDA(16384, 4, aoff1); mfma16t<4>(acc, a_, bK);
    __builtin_amdgcn_sched_barrier(0); VW2(); BARX();
  }

  // ---- peeled tail (tiles 10 buf0 / 11 buf1): drain at t-mph2; vmcnt clean ----
  {
    short8 a_[4];
    // t-mph1: buf0 ks0; stage A-11 x4 + B-11-k1 x2
    PH_LDA(0, 0, aoff0); PH_LDB(0, 0);
    gld16(sA0 + 704, &L[dA0 + 16384]); gld16(sA1 + 704, &L[dA1 + 16384]);
    gld16(sA2 + 704, &L[dA2 + 16384]); gld16(sA3 + 704, &L[dA3 + 16384]);
    gld16(sB0 + 736, &L[dB0 + 16384 + 8192]); gld16(sB1 + 736, &L[dB1 + 16384 + 8192]);
    BARX(); mfma16t<0>(acc, a_, bK);
    PH_LDA(0, 4, aoff0); mfma16t<4>(acc, a_, bK); BARX();
    // t-mph2: buf0 ks1; full drain (tile 11 all landed)
    PH_LDA(0, 0, aoff1); PH_LDB(0, 1);
    BARX(); mfma16t<0>(acc, a_, bK);
    PH_LDA(0, 4, aoff1); mfma16t<4>(acc, a_, bK);
    __builtin_amdgcn_sched_barrier(0);
    asm volatile("s_waitcnt vmcnt(0)" ::: "memory");
    BARX();
    // t-mph3: buf1 ks0
    PH_LDA(16384, 0, aoff0); PH_LDB(16384, 0);
    BARX(); mfma16t<0>(acc, a_, bK);
    PH_LDA(16384, 4, aoff0); mfma16t<4>(acc, a_, bK); BARX();
    // t-mph4: buf1 ks1
    PH_LDA(16384, 0, aoff1); PH_LDB(16384, 1);
    BARX(); mfma16t<0>(acc, a_, bK);
    PH_LDA(16384, 4, aoff1); mfma16t<4>(acc, a_, bK); BARX();
  }

  // ---- epilogue ----
  const int mrow = m0 + wm2 * 128 + l15;
  const int ncb  = n0 + wn4 * 64 + 4 * lq;
  if (epi == 0) {
    #pragma unroll
    for (int mi = 0; mi < 8; mi++) {
      unsigned short* Crow = Cb + (size_t)(mrow + 16*mi) * N + ncb;
      #pragma unroll
      for (int ni = 0; ni < 4; ni++) {
        if (ncb + 16*ni < N) {
          f32x4 v = acc[mi][ni];
          *(ull*)(Crow + 16*ni) = pack4bf(v[0], v[1], v[2], v[3]);
        }
      }
    }
  } else {            // epi==1: sigmoid(C + bias[n]) (N=768)
    f32x4 bb[4];
    #pragma unroll
    for (int ni = 0; ni < 4; ni++) bb[ni] = *(const f32x4*)(bias + ncb + 16*ni);
    #pragma unroll
    for (int mi = 0; mi < 8; mi++) {
      unsigned short* Crow = Cb + (size_t)(mrow + 16*mi) * N + ncb;
      #pragma unroll
      for (int ni = 0; ni < 4; ni++) {
        f32x4 v = acc[mi][ni];
        *(ull*)(Crow + 16*ni) = pack4bf(
            sigm(v[0] + bb[ni][0]), sigm(v[1] + bb[ni][1]),
            sigm(v[2] + bb[ni][2]), sigm(v[3] + bb[ni][3]));
      }
    }
  }
}

// in_proj (13n x 32m tiles) + gate (3n x 32m): 256 persistent blocks x 2 STATIC
// tiles (same XCD, same A-panel pair -> L2-hot tile2 prologue). R2-proven mapping.
__global__ __launch_bounds__(512, 2) void k_ipg256(
    const unsigned short* __restrict__ XN, const unsigned short* __restrict__ WIT,
    unsigned short* __restrict__ ZXb,
    const unsigned short* __restrict__ WGT, unsigned short* __restrict__ Gb,
    const float* __restrict__ gate_b)
{
  __shared__ alignas(16) unsigned short L[65536];   // 128 KiB
  const int bid = blockIdx.x;
  const int xcd = bid & 7;
  #pragma unroll 1
  for (int t = 0; t < 2; t++) {
    const int within = (bid >> 3) + 32 * t;
    const unsigned short* Btp; unsigned short* Cbp;
    int N_, m0, n0, epi; const float* bias;
    if (within < 52) {
      Btp = WIT; Cbp = ZXb; N_ = DINPROJ; epi = 0; bias = nullptr;
      m0 = (xcd * 4 + (within & 3)) * 256;
      n0 = (within >> 2) * 256;
    } else {
      const int w2 = within - 52;
      Btp = WGT; Cbp = Gb; N_ = DMODEL; epi = 1; bias = gate_b;
      m0 = (xcd * 4 + (w2 & 3)) * 256;
      n0 = (w2 >> 2) * 256;
    }
    gemm256(XN, Btp, Cbp, N_, m0, n0, epi, bias, L);
  }
}

// ============ 128x256 4-PHASE GEMM (512 thr, counted vmcnt(2), param K) ==========
// (R6-proven. 8 waves 2Mx4N of 64x64; LDS 96KiB; counted VW2 keeps 2 loads in
//  flight across every wait; tiles >= NT clamp to k=0 junk, drained at exit.)
__device__ __forceinline__ void gemm512(const unsigned short* __restrict__ A,
    const unsigned short* __restrict__ Bt, float* __restrict__ Cf,
    unsigned short* __restrict__ Cb, int N, int K, int NT, int m0, int n0,
    int epi, const float* __restrict__ bias, const float* __restrict__ resid,
    const unsigned short* __restrict__ gmul, const float* __restrict__ rsc,
    unsigned short* L)
{
  const int tid = threadIdx.x;
  const int lane = tid & 63, w = tid >> 6;
  const int wm2 = w >> 2, wn4 = w & 3;
  const int l15 = lane & 15, lq = lane >> 4;
  const int aswz = l15 & 7;
  const int aoff0 = ((lq)     ^ aswz) * 8;
  const int aoff1 = ((lq + 4) ^ aswz) * 8;
  const int boff  = (lq ^ ((l15 >> 1) & 3)) * 8;
  const int arow = (wm2 * 64 + l15) * 64;          // + mi*1024 + buf*8192 + aoff
  const int brow = 16384 + (wn4 * 64 + l15) * 32;  // + buf*16384 + ks*8192 + ni*512 + boff
  const int w512 = w * 512;

  const int lr3 = lane >> 3, lr2 = lane >> 2;
  const int gqA = ((lane & 7) ^ lr3) * 8;
  const int gqB = ((lane & 3) ^ (lr3 & 3)) * 8;
  const unsigned short* sAlo = A + (size_t)(m0 + 8*w + lr3) * K + gqA;   // rows 0-63
  const unsigned short* sAhi = sAlo + (size_t)64 * K;                    // rows 64-127
  const unsigned short* sB0 = Bt + (size_t)(n0 + 16*w + lr2) * K + gqB;  // rows 0-127
  const unsigned short* sB1 = sB0 + (size_t)128 * K;                     // rows 128-255

  f32x4 acc[4][4];
  #pragma unroll
  for (int i = 0; i < 4; i++)
    #pragma unroll
    for (int jj = 0; jj < 4; jj++) acc[i][jj] = (f32x4){0.f, 0.f, 0.f, 0.f};
  short8 a_[4], bK[4];

  // ---- prologue: tile0 full (6) + tile1 B-k0 (2); keep 2 in flight ----
  gld16(sAlo, &L[w512]); gld16(sAhi, &L[4096 + w512]);
  gld16(sB0, &L[16384 + w512]); gld16(sB1, &L[20480 + w512]);
  gld16(sB0 + 32, &L[24576 + w512]); gld16(sB1 + 32, &L[28672 + w512]);
  gld16(sB0 + 64, &L[32768 + w512]); gld16(sB1 + 64, &L[36864 + w512]);
  VW2();
  FENCE(); __builtin_amdgcn_s_barrier(); FENCE(); __builtin_amdgcn_sched_barrier(0);

  #pragma unroll 1
  for (int j = 0; j < NT/2; j++) {
    const int kO  = (2*j + 1) * 64;
    const int kE2 = (2*j + 2 < NT) ? (2*j + 2) * 64 : 0;
    const int kO2 = (2*j + 3 < NT) ? (2*j + 3) * 64 : 0;

    // ph1: buf0 ks0; stage A-O (buf1) + B-O-k1 (buf1)
    #pragma unroll
    for (int mi = 0; mi < 4; mi++) a_[mi] = lds8(L, arow + mi*1024 + aoff0);
    #pragma unroll
    for (int ni = 0; ni < 4; ni++) bK[ni] = lds8(L, brow + ni*512 + boff);
    gld16(sAlo + kO, &L[8192 + w512]); gld16(sAhi + kO, &L[12288 + w512]);
    gld16(sB0 + kO + 32, &L[40960 + w512]); gld16(sB1 + kO + 32, &L[45056 + w512]);
    BARX(); mfma16t<0>(acc, a_, bK); BARX();
    // ph2: buf0 ks1; stage B-E'-k0 (buf0); WAIT(2)
    #pragma unroll
    for (int mi = 0; mi < 4; mi++) a_[mi] = lds8(L, arow + mi*1024 + aoff1);
    #pragma unroll
    for (int ni = 0; ni < 4; ni++) bK[ni] = lds8(L, brow + 8192 + ni*512 + boff);
    gld16(sB0 + kE2, &L[16384 + w512]); gld16(sB1 + kE2, &L[20480 + w512]);
    BARX(); mfma16t<0>(acc, a_, bK);
    __builtin_amdgcn_sched_barrier(0); VW2(); BARX();
    // ph3: buf1 ks0; stage A-E' (buf0) + B-E'-k1 (buf0)
    #pragma unroll
    for (int mi = 0; mi < 4; mi++) a_[mi] = lds8(L, 8192 + arow + mi*1024 + aoff0);
    #pragma unroll
    for (int ni = 0; ni < 4; ni++) bK[ni] = lds8(L, brow + 16384 + ni*512 + boff);
    gld16(sAlo + kE2, &L[w512]); gld16(sAhi + kE2, &L[4096 + w512]);
    gld16(sB0 + kE2 + 32, &L[24576 + w512]); gld16(sB1 + kE2 + 32, &L[28672 + w512]);
    BARX(); mfma16t<0>(acc, a_, bK); BARX();
    // ph4: buf1 ks1; stage B-O'-k0 (buf1); WAIT(2)
    #pragma unroll
    for (int mi = 0; mi < 4; mi++) a_[mi] = lds8(L, 8192 + arow + mi*1024 + aoff1);
    #pragma unroll
    for (int ni = 0; ni < 4; ni++) bK[ni] = lds8(L, brow + 16384 + 8192 + ni*512 + boff);
    gld16(sB0 + kO2, &L[32768 + w512]); gld16(sB1 + kO2, &L[36864 + w512]);
    BARX(); mfma16t<0>(acc, a_, bK);
    __builtin_amdgcn_sched_barrier(0); VW2(); BARX();
  }
  asm volatile("s_waitcnt vmcnt(0)" ::: "memory");

  // ---- epilogue: lane holds cols (ncb+16ni .. +3) of row (mrow+16mi) ----
  const int mrowb = m0 + wm2 * 64 + l15;
  const int ncb   = n0 + wn4 * 64 + 4 * lq;
  if (epi == 3) {           // RMS rsqrt(row) * gate -> bf16
    #pragma unroll
    for (int mi = 0; mi < 4; mi++) {
      const int row = mrowb + 16*mi;
      const float sc = rsqrtf(rsc[row] * (1.f / DINNER) + EPSF);
      unsigned short* Crow = Cb + (size_t)row * N + ncb;
      const unsigned short* Grow = gmul + (size_t)row * N + ncb;
      #pragma unroll
      for (int ni = 0; ni < 4; ni++) {
        f32x4 v = acc[mi][ni];
        ull gv = *(const ull*)(Grow + 16*ni);
        *(ull*)(Crow + 16*ni) = pack4bf(
            v[0] * sc * bf2f((unsigned short)(gv)),
            v[1] * sc * bf2f((unsigned short)(gv >> 16)),
            v[2] * sc * bf2f((unsigned short)(gv >> 32)),
            v[3] * sc * bf2f((unsigned short)(gv >> 48)));
      }
    }
  } else {                  // epi==2: C + bias[n] + resid[m][n] -> f32 out
    f32x4 bb[4];
    #pragma unroll
    for (int ni = 0; ni < 4; ni++) bb[ni] = *(const f32x4*)(bias + ncb + 16*ni);
    #pragma unroll
    for (int mi = 0; mi < 4; mi++) {
      const int row = mrowb + 16*mi;
      float* Co = Cf + (size_t)row * N + ncb;
      const float* Rr = resid + (size_t)row * N + ncb;
      #pragma unroll
      for (int ni = 0; ni < 4; ni++) {
        f32x4 v = acc[mi][ni];
        f32x4 rv = *(const f32x4*)(Rr + 16*ni);
        f32x4 o = { v[0] + bb[ni][0] + rv[0], v[1] + bb[ni][1] + rv[1],
                    v[2] + bb[ni][2] + rv[2], v[3] + bb[ni][3] + rv[3] };
        *(f32x4*)(Co + 16*ni) = o;
      }
    }
  }
}

// grid 192 = 8 xcd x 8 m-slots x 3 n; A's 3 n-tiles land on the same XCD (L2-hot A).
__global__ __launch_bounds__(512, 2) void k_gemm512(const unsigned short* __restrict__ A,
    const unsigned short* __restrict__ Bt, float* __restrict__ Cf,
    unsigned short* __restrict__ Cb, int N, int K, int NT, int epi,
    const float* __restrict__ bias, const float* __restrict__ resid,
    const unsigned short* __restrict__ gmul, const float* __restrict__ rsc)
{
  __shared__ alignas(16) unsigned short L[49152];   // 96 KiB
  const int bid = blockIdx.x;
  const int xcd = bid & 7, within = bid >> 3;       // 0..23
  const int m0 = (xcd * 8 + (within & 7)) * 128;
  const int n0 = (within >> 3) * 256;
  gemm512(A, Bt, Cf, Cb, N, K, NT, m0, n0, epi, bias, resid, gmul, rsc, L);
}

// ---------------- LDS-tiled causal conv1d (K=4) + SiLU (R2-proven) ---------------
__global__ __launch_bounds__(256) void k_conv(const unsigned short* __restrict__ zx,
    const float* __restrict__ cw, const float* __restrict__ cb,
    unsigned short* __restrict__ out)
{
  __shared__ alignas(8) unsigned short tile[67][132];   // pitch 264 B
  const int tid = threadIdx.x;
  const int c0 = blockIdx.x * 128;          // 13 tiles x 128 = 1664 = CONVD
  const int tc = blockIdx.y;                // 128 token-chunks of 64
  const int t0 = tc * 64;
  const bool haloOK = (tc & 63) != 0;       // chunk 0 of each batch has no halo
  for (int i = tid; i < 67 * 16; i += 256) {
    int row = i >> 4, g = i & 15;
    ull v0 = 0, v1 = 0;
    if (row >= 3 || haloOK) {
      const unsigned short* p = zx + (size_t)(t0 - 3 + row) * DINPROJ + DINNER + c0 + g * 8;
      v0 = *(const ull*)p;
      v1 = *(const ull*)(p + 4);
    }
    *(ull*)(&tile[row][g * 8])     = v0;
    *(ull*)(&tile[row][g * 8 + 4]) = v1;
  }
  __syncthreads();
  const int ch0 = (tid & 63) * 2;           // 0..126
  const int trow = tid >> 6;                // 0..3
  const int cg = c0 + ch0;
  float cw0[4], cw1[4];
  #pragma unroll
  for (int k = 0; k < 4; k++) { cw0[k] = cw[cg * 4 + k]; cw1[k] = cw[(cg + 1) * 4 + k]; }
  const float cb0 = cb[cg], cb1 = cb[cg + 1];
  #pragma unroll
  for (int q = 0; q < 16; q++) {
    int tq = trow * 16 + q;
    float a0 = cb0, a1 = cb1;
    #pragma unroll
    for (int k = 0; k < 4; k++) {
      unsigned int u = *(const unsigned int*)(&tile[tq + k][ch0]);
      a0 += bf2f((unsigned short)u) * cw0[k];
      a1 += bf2f((unsigned short)(u >> 16)) * cw1[k];
    }
    float s0 = a0 * sigm(a0), s1 = a1 * sigm(a1);
    *(unsigned int*)(out + (size_t)(t0 + tq) * CONVD + cg) =
        (unsigned int)f2bf(s0) | ((unsigned int)f2bf(s1) << 16);
  }
}

// ---------------- SSD pass 1 (MFMA): S[bh,c][n][p] (bf16) (R2-proven) ------------
__global__ __launch_bounds__(256) void k_chunkstate(const unsigned short* __restrict__ zx,
    const unsigned short* __restrict__ xbcc, const float* __restrict__ dt_bias,
    const float* __restrict__ A_log, unsigned short* __restrict__ S, float* __restrict__ CD)
{
  const int c = blockIdx.x, bh = blockIdx.y;
  const int b = bh / NH, h = bh % NH;
  const int tid = threadIdx.x;
  const int lane = tid & 63, w = tid >> 6;
  const int l15 = lane & 15, lq = lane >> 4;
  __shared__ float wv_[64];
  __shared__ alignas(16) unsigned short Bwt[64][LP];  // [n][s]
  __shared__ alignas(16) unsigned short Xt [64][LP];  // [p][s]

  if (tid < 64) {                     // wave 0: dt, prefix-scan of Lc
    int t = c * 64 + tid;
    float xx = bf2f(zx[((size_t)(b * SEQ + t)) * DINPROJ + (DINNER + CONVD) + h]) + dt_bias[h];
    float dt_ = (xx > 15.f) ? xx : log1pf(__expf(xx));
    float Ah = -__expf(A_log[h]);
    float v = dt_ * Ah;
    #pragma unroll
    for (int off = 1; off < 64; off <<= 1) {
      float u = __shfl_up(v, off);
      if (tid >= off) v += u;
    }
    float L63 = __shfl(v, 63);
    wv_[tid] = __expf(L63 - v) * dt_;
    if (tid == 63) CD[bh * 64 + c] = __expf(v);
  }
  ull braw[4];
  #pragma unroll
  for (int it = 0; it < 4; it++) {
    int i4 = tid + 256 * it;
    int s = i4 >> 4, q4 = (i4 & 15) * 4;
    size_t rb = ((size_t)(b * SEQ) + c * 64 + s) * CONVD;
    braw[it] = *(const ull*)(xbcc + rb + DINNER + q4);
    unsigned short xs[4];
    *(ull*)xs = *(const ull*)(xbcc + rb + h * HD + q4);
    Xt[q4+0][s] = xs[0]; Xt[q4+1][s] = xs[1]; Xt[q4+2][s] = xs[2]; Xt[q4+3][s] = xs[3];
  }
  __syncthreads();
  #pragma unroll
  for (int it = 0; it < 4; it++) {
    int i4 = tid + 256 * it;
    int s = i4 >> 4, q4 = (i4 & 15) * 4;
    float wsc = wv_[s];
    unsigned short us[4];
    *(ull*)us = braw[it];
    Bwt[q4+0][s] = f2bf(bf2f(us[0]) * wsc);
    Bwt[q4+1][s] = f2bf(bf2f(us[1]) * wsc);
    Bwt[q4+2][s] = f2bf(bf2f(us[2]) * wsc);
    Bwt[q4+3][s] = f2bf(bf2f(us[3]) * wsc);
  }
  __syncthreads();
  const int n0 = 16 * w;
  short8 a0 = *(const short8*)(&Bwt[n0 + l15][lq * 8]);
  short8 a1 = *(const short8*)(&Bwt[n0 + l15][32 + lq * 8]);
  size_t sb = ((size_t)bh * 64 + c) * 4096;
  #pragma unroll
  for (int pt = 0; pt < 4; pt++) {
    f32x4 acc = (f32x4){0.f, 0.f, 0.f, 0.f};
    short8 b0 = *(const short8*)(&Xt[16*pt + l15][lq * 8]);
    short8 b1 = *(const short8*)(&Xt[16*pt + l15][32 + lq * 8]);
    acc = __builtin_amdgcn_mfma_f32_16x16x32_bf16(a0, b0, acc, 0, 0, 0);
    acc = __builtin_amdgcn_mfma_f32_16x16x32_bf16(a1, b1, acc, 0, 0, 0);
    #pragma unroll
    for (int r = 0; r < 4; r++) {
      int n = n0 + 4*lq + r, p = 16*pt + l15;
      S[sb + (size_t)n * 64 + p] = f2bf(acc[r]);
    }
  }
}

// ---------------- SSD pass 2: chunk recurrence (16-batched prefetch) -------------
__global__ __launch_bounds__(256) void k_chunkrec(unsigned short* __restrict__ S,
    const float* __restrict__ CD)
{
  const int bh = blockIdx.x >> 4, part = blockIdx.x & 15;
  const int e = part * 256 + threadIdx.x;
  float g = 0.f;
  size_t base = (size_t)bh * 64 * 4096 + e;
  const float* cdp = CD + bh * 64;
  #pragma unroll 1
  for (int cb2 = 0; cb2 < 64; cb2 += 16) {
    unsigned short sv[16];
    #pragma unroll
    for (int u = 0; u < 16; u++) sv[u] = S[base + (size_t)(cb2 + u) * 4096];
    #pragma unroll
    for (int u = 0; u < 16; u++) {
      float s = bf2f(sv[u]);
      S[base + (size_t)(cb2 + u) * 4096] = f2bf(g);   // slot c now holds G_c
      g = cdp[cb2 + u] * g + s;
    }
  }
}

// ---------------- SSD pass 3 (MFMA): y*silu(z) fused, ssq atomics ----------------
__global__ __launch_bounds__(256) void k_chunkout(const unsigned short* __restrict__ zx,
    const unsigned short* __restrict__ xbcc, const unsigned short* __restrict__ S,
    const float* __restrict__ dt_bias, const float* __restrict__ A_log,
    const float* __restrict__ Dp, unsigned short* __restrict__ Y,
    float* __restrict__ ssq)
{
  const int c = blockIdx.x, bh = blockIdx.y;
  const int b = bh / NH, h = bh % NH;
  const int tid = threadIdx.x;
  const int lane = tid & 63, w = tid >> 6;
  const int l15 = lane & 15, lq = lane >> 4;
  __shared__ float dts[64], Lc[64], ein[64];
  __shared__ alignas(16) unsigned short Cs  [64][LP];  // [i][n]
  __shared__ alignas(16) unsigned short BsPs[64][LP];  // [s][n], then P[i][s]
  __shared__ alignas(16) unsigned short Xt  [64][LP];  // [p][s]
  __shared__ alignas(16) unsigned short Gt  [64][LP];  // [p][n]

  if (tid < 64) {                     // wave 0: dt, prefix-scan of Lc
    int t = c * 64 + tid;
    float xx = bf2f(zx[((size_t)(b * SEQ + t)) * DINPROJ + (DINNER + CONVD) + h]) + dt_bias[h];
    float dt_ = (xx > 15.f) ? xx : log1pf(__expf(xx));
    dts[tid] = dt_;
    float Ah = -__expf(A_log[h]);
    float v = dt_ * Ah;
    #pragma unroll
    for (int off = 1; off < 64; off <<= 1) {
      float u = __shfl_up(v, off);
      if (tid >= off) v += u;
    }
    Lc[tid] = v;
    ein[tid] = __expf(v);
  }
  const size_t gslot = ((size_t)bh * 64 + c) * 4096;
  #pragma unroll
  for (int it = 0; it < 4; it++) {
    int i4 = tid + 256 * it;
    int rr = i4 >> 4, q4 = (i4 & 15) * 4;
    size_t rb = ((size_t)(b * SEQ) + c * 64 + rr) * CONVD;
    *(ull*)&Cs[rr][q4]   = *(const ull*)(xbcc + rb + (DINNER + DSTATE) + q4);
    *(ull*)&BsPs[rr][q4] = *(const ull*)(xbcc + rb + DINNER + q4);
    unsigned short xs[4];
    *(ull*)xs = *(const ull*)(xbcc + rb + h * HD + q4);
    Xt[q4+0][rr] = xs[0]; Xt[q4+1][rr] = xs[1]; Xt[q4+2][rr] = xs[2]; Xt[q4+3][rr] = xs[3];
    unsigned short gs[4];
    *(ull*)gs = *(const ull*)(S + gslot + (size_t)i4 * 4);
    Gt[q4+0][rr] = gs[0]; Gt[q4+1][rr] = gs[1]; Gt[q4+2][rr] = gs[2]; Gt[q4+3][rr] = gs[3];
  }
  __syncthreads();
  // ---- matmul1: G[i][s] = sum_n C[i][n] B[s][n]; apply causal decay mask -> P ----
  const int i0 = 16 * w;
  short8 ac0 = *(const short8*)(&Cs[i0 + l15][lq * 8]);
  short8 ac1 = *(const short8*)(&Cs[i0 + l15][32 + lq * 8]);
  float pp[4][4];
  #pragma unroll
  for (int st = 0; st < 4; st++) {
    f32x4 g = (f32x4){0.f, 0.f, 0.f, 0.f};
    if (st <= w) {                                   // wave-uniform causal skip
      short8 b0 = *(const short8*)(&BsPs[16*st + l15][lq * 8]);
      short8 b1 = *(const short8*)(&BsPs[16*st + l15][32 + lq * 8]);
      g = __builtin_amdgcn_mfma_f32_16x16x32_bf16(ac0, b0, g, 0, 0, 0);
      g = __builtin_amdgcn_mfma_f32_16x16x32_bf16(ac1, b1, g, 0, 0, 0);
    }
    #pragma unroll
    for (int r = 0; r < 4; r++) {
      int i = i0 + 4*lq + r, s = 16*st + l15;
      pp[st][r] = (s <= i) ? g[r] * __expf(Lc[i] - Lc[s]) * dts[s] : 0.f;
    }
  }
  __syncthreads();                                   // all waves done reading Bs
  #pragma unroll
  for (int st = 0; st < 4; st++)
    #pragma unroll
    for (int r = 0; r < 4; r++)
      BsPs[i0 + 4*lq + r][16*st + l15] = f2bf(pp[st][r]);   // P[i][s], s contiguous
  __syncthreads();
  // ---- matmul2+3: Y[i][p] = (P@X + ein[i]*(C@G) + D*x) * silu(z) ----
  short8 ap0 = *(const short8*)(&BsPs[i0 + l15][lq * 8]);
  short8 ap1 = *(const short8*)(&BsPs[i0 + l15][32 + lq * 8]);
  const float Dh = Dp[h];
  float sq[4] = {0.f, 0.f, 0.f, 0.f};
  #pragma unroll
  for (int pt = 0; pt < 4; pt++) {
    const int p0 = 16 * pt;
    f32x4 y1 = (f32x4){0.f, 0.f, 0.f, 0.f};
    f32x4 y2 = (f32x4){0.f, 0.f, 0.f, 0.f};
    short8 bx0 = *(const short8*)(&Xt[p0 + l15][lq * 8]);
    y1 = __builtin_amdgcn_mfma_f32_16x16x32_bf16(ap0, bx0, y1, 0, 0, 0);
    if (w >= 2) {                                    // P rows of wave w have k < 16(w+1)
      short8 bx1 = *(const short8*)(&Xt[p0 + l15][32 + lq * 8]);
      y1 = __builtin_amdgcn_mfma_f32_16x16x32_bf16(ap1, bx1, y1, 0, 0, 0);
    }
    short8 bg0 = *(const short8*)(&Gt[p0 + l15][lq * 8]);
    short8 bg1 = *(const short8*)(&Gt[p0 + l15][32 + lq * 8]);
    y2 = __builtin_amdgcn_mfma_f32_16x16x32_bf16(ac0, bg0, y2, 0, 0, 0);
    y2 = __builtin_amdgcn_mfma_f32_16x16x32_bf16(ac1, bg1, y2, 0, 0, 0);
    #pragma unroll
    for (int r = 0; r < 4; r++) {
      int i = i0 + 4*lq + r, p = p0 + l15;
      float xv = bf2f(Xt[p][i]);
      float o = y1[r] + ein[i] * y2[r] + Dh * xv;
      size_t row = (size_t)(b * SEQ) + c * 64 + i;
      float zv = bf2f(zx[row * DINPROJ + h * HD + p]);
      float og = o * (zv * sigm(zv));
      Y[row * DINNER + h * HD + p] = f2bf(og);
      sq[r] += og * og;
    }
  }
  // per-row sum of squares: reduce over the 16 l15 lanes, 1 atomic/row
  #pragma unroll
  for (int r = 0; r < 4; r++) {
    float s = sq[r];
    s += __shfl_xor(s, 1); s += __shfl_xor(s, 2);
    s += __shfl_xor(s, 4); s += __shfl_xor(s, 8);
    if (l15 == 0)
      atomicAdd(ssq + (size_t)(b * SEQ) + c * 64 + (i0 + 4*lq + r), s);
  }
}

// ---------------- launch ----------------------------------------------------------
extern "C" void kernel_launch(void* const* d_in, const int* in_sizes, int n_in,
                              void* d_out, int out_size, void* d_ws, size_t ws_size,
                              hipStream_t stream)
{
  const float* x         = (const float*)d_in[0];
  const float* ln_w      = (const float*)d_in[1];
  const float* ln_b      = (const float*)d_in[2];
  const float* in_proj_w = (const float*)d_in[3];
  const float* conv_w    = (const float*)d_in[4];
  const float* conv_b    = (const float*)d_in[5];
  const float* dt_bias   = (const float*)d_in[6];
  const float* A_log     = (const float*)d_in[7];
  const float* D_param   = (const float*)d_in[8];
  const float* rms_w     = (const float*)d_in[9];
  const float* out_proj_w= (const float*)d_in[10];
  const float* gate_w    = (const float*)d_in[11];
  const float* gate_b    = (const float*)d_in[12];
  const float* out_w     = (const float*)d_in[13];
  const float* out_b     = (const float*)d_in[14];
  float* out = (float*)d_out;
  char* ws = (char*)d_ws;

  // ---- workspace layout (bytes). peak = 177,848,320 B (~170 MB) — R2 layout ----
  const size_t WS_NEEDED = 177848320ull;
  if (ws_size < WS_NEEDED) return;

  unsigned short* XN    = (unsigned short*)(ws + 0);
  unsigned short* WIT   = (unsigned short*)(ws + 12582912);
  unsigned short* WGT   = (unsigned short*)(ws + 17534976);
  unsigned short* WOPT  = (unsigned short*)(ws + 18714624);
  unsigned short* WOT   = (unsigned short*)(ws + 21073920);
  unsigned short* ZXb   = (unsigned short*)(ws + 22253568);   // 8192x3224 bf16
  unsigned short* XBCCb = (unsigned short*)(ws + 75075584);   // 8192x1664 bf16
  unsigned short* Sb    = (unsigned short*)(ws + 102338560);  // 3072x4096 bf16 (25.2MB)
  unsigned short* Gb    = (unsigned short*)(ws + 127504384);  // 8192x768 bf16 (gate out)
  float*          ssq   = (float*)(ws + 140087296);           // 8192 f32 row sum-sq
  float*          CD    = (float*)(ws + 152670208);           // 3072 f32
  unsigned short* Yb    = (unsigned short*)(ws + 152682496);  // 8192x1536 bf16 (y*silu(z))
  // overlay:
  unsigned short* YG    = (unsigned short*)(ws + 75075584);   // in XBCCb region (dead after chunkout)

  // 1) merged prep: LN (8192) + 4 weight transposes (4728) + ssq zero
  k_prep<<<NTOK + 4728, 256, 0, stream>>>(x, ln_w, ln_b, XN, ssq,
                                          in_proj_w, WIT, gate_w, WGT,
                                          out_proj_w, WOPT, out_w, WOT, rms_w);
  // 2) in_proj + gate GEMMs: 256 persistent blocks x 2 static tiles, 4-phase core
  k_ipg256<<<256, 512, 0, stream>>>(XN, WIT, ZXb, WGT, Gb, gate_b);
  // 3) LDS-tiled causal conv + silu (bf16 -> bf16)
  k_conv<<<dim3(13, 128), 256, 0, stream>>>(ZXb, conv_w, conv_b, XBCCb);
  // 4-6) SSD scan (S in bf16; chunkout fuses y*silu(z) + ssq)
  k_chunkstate<<<dim3(NCHUNK, BSZ * NH), 256, 0, stream>>>(ZXb, XBCCb, dt_bias, A_log, Sb, CD);
  k_chunkrec<<<BSZ * NH * 16, 256, 0, stream>>>(Sb, CD);
  k_chunkout<<<dim3(NCHUNK, BSZ * NH), 256, 0, stream>>>(ZXb, XBCCb, Sb, dt_bias, A_log,
                                                         D_param, Yb, ssq);
  // 7) out_proj GEMM (128x256 4-phase core): RMS rsqrt * gate epilogue -> YG bf16
  k_gemm512<<<192, 512, 0, stream>>>(Yb, WOPT, nullptr, YG, DMODEL, DINNER, 24, 3,
                                     nullptr, nullptr, Gb, ssq);
  // 8) final GEMM (128x256 4-phase core): + bias + residual -> f32 d_out
  k_gemm512<<<192, 512, 0, stream>>>(YG, WOT, out, nullptr, DMODEL, DMODEL, 12, 2,
                                     out_b, x, nullptr, nullptr);
}